// Round 20
// baseline (643.167 us; speedup 1.0000x reference)
//
#include <hip/hip_runtime.h>
#include <math.h>

#define LN    524288        // signal length, 2^19
#define N1    512           // first-FFT length (column FFT)
#define N2    1024          // second-FFT length (row FFT)
#define NCH   129
#define DSR   80            // downsample rate
#define NOUT  6553          // output frames per channel
#define OB2   64            // outputs per IIR block
#define NBLK  103           // ceil(NOUT/OB2)
#define SPB   (OB2*DSR)     // 5120 samples per IIR block
#define TPW   20            // samples per thread in IIR
#define NPAIR 65            // ceil(129/2) channel pairs
#define KTAIL 48            // LN - NOUT*DSR
#define SB    1024          // build_w6 segment length per block
#define LMAP(i) ((i) + ((i) >> 3))   // LDS bank-spread map (2-way max)
#define SWZ(p)  ((p) ^ ((((p) >> 5) & 1) * 31))   // bank swizzle

__device__ __forceinline__ float2 cmulf(float2 a, float2 b) {
    return make_float2(a.x*b.x - a.y*b.y, a.x*b.y + a.y*b.x);
}

// fast |x|^a * sign(x): hardware log2/exp2 (x=0 -> -inf -> 0, correct)
__device__ __forceinline__ float powsign(float x, float a) {
    float m = __builtin_amdgcn_exp2f(a * __builtin_amdgcn_logf(fabsf(x)));
    return copysignf(m, x);
}

// ---------------- pack real x into complex buffer ----------------
__global__ void pack_x(const float* __restrict__ x, float2* __restrict__ dst) {
    int i = blockIdx.x * 256 + threadIdx.x;
    dst[i] = make_float2(x[i], 0.f);
}

// ---------------- tiled complex transpose (forward path only) ----------------
__global__ void transpose_c(const float2* __restrict__ src, float2* __restrict__ dst,
                            int R, int Cc) {
    __shared__ float2 tile[32][33];
    size_t boff = (size_t)blockIdx.z * LN;
    src += boff; dst += boff;
    int x  = blockIdx.x * 32 + threadIdx.x;
    int y0 = blockIdx.y * 32 + threadIdx.y;
#pragma unroll
    for (int i = 0; i < 32; i += 8)
        tile[threadIdx.y + i][threadIdx.x] = src[(size_t)(y0 + i) * Cc + x];
    __syncthreads();
    int xo  = blockIdx.y * 32 + threadIdx.x;
    int yo0 = blockIdx.x * 32 + threadIdx.y;
#pragma unroll
    for (int i = 0; i < 32; i += 8)
        dst[(size_t)(yo0 + i) * R + xo] = tile[threadIdx.x][threadIdx.y + i];
}

// ---------------- LDS Stockham radix-2 row FFT (forward path only) -----
template<int M, int SIGN, int TW>
__global__ __launch_bounds__(256) void fft_rows(const float2* __restrict__ src,
                                                float2* __restrict__ dst,
                                                int rows_per_batch) {
    __shared__ __align__(16) float2 ping[M];
    __shared__ __align__(16) float2 pong[M];
    __shared__ float2 twid[M];
    size_t rowg = blockIdx.x;
    const float2* srow = src + rowg * M;
    float2* drow = dst + rowg * M;
    int row = (int)(rowg % (size_t)rows_per_batch);
    int t = threadIdx.x;
    const float4* s4 = (const float4*)srow;
    for (int ii = t; ii < M/2; ii += 256)
        *(float4*)&ping[2*ii] = s4[ii];
    for (int i = t; i < M; i += 256) {
        if (i >= 1) {
            int h = 1 << (31 - __clz((unsigned)i));
            float ang = (float)SIGN * 3.14159265358979323846f * (float)(i - h) / (float)h;
            float s, c; __sincosf(ang, &s, &c);
            twid[i] = make_float2(c, s);
        }
    }
    __syncthreads();
    float2* a = ping;
    float2* b = pong;
    for (int Ns = 1; Ns < M; Ns <<= 1) {
        for (int j = t; j < M/2; j += 256) {
            int jm = j & (Ns - 1);
            float2 v0 = a[j];
            float2 v1 = a[j + M/2];
            float2 tw = twid[Ns + jm];
            float2 w = make_float2(v1.x*tw.x - v1.y*tw.y, v1.x*tw.y + v1.y*tw.x);
            int d0 = ((j & ~(Ns - 1)) << 1) | jm;
            b[d0]      = make_float2(v0.x + w.x, v0.y + w.y);
            b[d0 + Ns] = make_float2(v0.x - w.x, v0.y - w.y);
        }
        __syncthreads();
        float2* tmp = a; a = b; b = tmp;
    }
    if (TW) {
        const float c2pi = 6.28318530717958647692f / (float)LN;
        for (int i = t; i < M; i += 256) {
            float2 v = a[i];
            unsigned prod = ((unsigned)row * (unsigned)i) & (unsigned)(LN - 1);
            float ang = (float)SIGN * c2pi * (float)prod;
            float s, c;
            __sincosf(ang, &s, &c);
            drow[i] = make_float2(v.x*c - v.y*s, v.x*s + v.y*c);
        }
    } else {
        float4* d4 = (float4*)drow;
        for (int ii = t; ii < M/2; ii += 256)
            d4[ii] = *(const float4*)&a[2*ii];
    }
}

// ---------------- Hermitian-combine W[k],W[L-k] from H,X ----------------
__device__ __forceinline__ void herm2(float2 X1,
                                      float har,  float hai,  float hbr,  float hbi,
                                      float har2, float hai2, float hbr2, float hbi2,
                                      bool hasB, float2& Wk, float2& WkL) {
    float2 a1 = make_float2(har*X1.x - hai*X1.y, har*X1.y + hai*X1.x);
    float2 a2 = make_float2(har2*X1.x + hai2*X1.y, hai2*X1.x - har2*X1.y);
    float yar = 0.5f*(a1.x + a2.x), yai = 0.5f*(a1.y - a2.y);
    float ybr = 0.f, ybi = 0.f;
    if (hasB) {
        float2 b1 = make_float2(hbr*X1.x - hbi*X1.y, hbr*X1.y + hbi*X1.x);
        float2 b2 = make_float2(hbr2*X1.x + hbi2*X1.y, hbi2*X1.x - hbr2*X1.y);
        ybr = 0.5f*(b1.x + b2.x); ybi = 0.5f*(b1.y - b2.y);
    }
    Wk  = make_float2(yar - ybi, yai + ybr);
    WkL = make_float2(yar + ybi, ybr - yai);
}

// ---- build_w6: Hermitian pairing, mirror seg in LDS, low seg in REGISTERS only ----
__global__ __launch_bounds__(256) void build_w6(const float* __restrict__ Hr,
                                                const float* __restrict__ Hi,
                                                const float2* __restrict__ X,
                                                float2* __restrict__ W, int pair0) {
    __shared__ float mirS[4][1160];
    int s0 = blockIdx.x * SB;            // [0, LN/2)
    int pl = blockIdx.y;
    int p  = pair0 + pl;
    int ca = 2*p, cb = 2*p + 1;
    bool hasB = (cb < NCH);
    const float* Hs0 = Hr + (size_t)ca * LN;
    const float* Hs1 = Hi + (size_t)ca * LN;
    const float* Hs2 = hasB ? (Hr + (size_t)cb * LN) : Hs0;
    const float* Hs3 = hasB ? (Hi + (size_t)cb * LN) : Hs1;
    const float* Hs[4] = {Hs0, Hs1, Hs2, Hs3};
    float2* Wp = W + (size_t)pl * LN;
    int t = threadIdx.x;
    int j4 = 4 * t;
    int mbase = LN - s0 - SB;            // mirror segment start

    float4 lowv[4];
#pragma unroll
    for (int a = 0; a < 4; a++) {
        lowv[a] = *(const float4*)&Hs[a][s0 + j4];
        float4 mv = *(const float4*)&Hs[a][mbase + j4];
        int lm = LMAP(j4);
        mirS[a][lm+0] = mv.x; mirS[a][lm+1] = mv.y; mirS[a][lm+2] = mv.z; mirS[a][lm+3] = mv.w;
    }
    if (t == 1 && s0 > 0) {
#pragma unroll
        for (int a = 0; a < 4; a++) mirS[a][LMAP(SB)] = Hs[a][LN - s0];
    }
    float nxt[4];
#pragma unroll
    for (int a = 0; a < 4; a++) nxt[a] = __shfl_down(lowv[a].x, 1);
    if ((t & 63) == 63) {
#pragma unroll
        for (int a = 0; a < 4; a++) nxt[a] = Hs[a][s0 + j4 + 4];
    }
    __syncthreads();

    float4 xa = *(const float4*)&X[s0 + j4];
    float4 xb = *(const float4*)&X[s0 + j4 + 2];
    float2 wlo[4];
#pragma unroll
    for (int d = 0; d < 4; d++) {
        int k = s0 + j4 + d;
        float2 Xk = (d == 0) ? make_float2(xa.x, xa.y) :
                    (d == 1) ? make_float2(xa.z, xa.w) :
                    (d == 2) ? make_float2(xb.x, xb.y) : make_float2(xb.z, xb.w);
        float hl[4] = { (d==0)?lowv[0].x:(d==1)?lowv[0].y:(d==2)?lowv[0].z:lowv[0].w,
                        (d==0)?lowv[1].x:(d==1)?lowv[1].y:(d==2)?lowv[1].z:lowv[1].w,
                        (d==0)?lowv[2].x:(d==1)?lowv[2].y:(d==2)?lowv[2].z:lowv[2].w,
                        (d==0)?lowv[3].x:(d==1)?lowv[3].y:(d==2)?lowv[3].z:lowv[3].w };
        if (k == 0) {
            float2 Ya = cmulf(make_float2(hl[0], hl[1]), Xk);
            float br = 0.f;
            if (hasB) { float2 Yb = cmulf(make_float2(hl[2], hl[3]), Xk); br = Yb.x; }
            wlo[d] = make_float2(Ya.x, br);
        } else {
            int jm = LMAP(SB - j4 - d);
            float2 Wk, WkL;
            herm2(Xk, hl[0], hl[1], hl[2], hl[3],
                      mirS[0][jm], mirS[1][jm], mirS[2][jm], mirS[3][jm], hasB, Wk, WkL);
            wlo[d] = Wk;
        }
    }
    *(float4*)&Wp[s0 + j4]     = make_float4(wlo[0].x, wlo[0].y, wlo[1].x, wlo[1].y);
    *(float4*)&Wp[s0 + j4 + 2] = make_float4(wlo[2].x, wlo[2].y, wlo[3].x, wlo[3].y);

    int e0 = SB - 4 - j4;
    float2 wmi[4];
#pragma unroll
    for (int d = 0; d < 4; d++) {
        int ee = e0 + d;
        int m  = mbase + ee;
        int jm = LMAP(ee);
        if (m == LN/2) {
            float2 Xv = X[LN/2];
            float2 Ya = cmulf(make_float2(mirS[0][jm], mirS[1][jm]), Xv);
            float br = 0.f;
            if (hasB) { float2 Yb = cmulf(make_float2(mirS[2][jm], mirS[3][jm]), Xv); br = Yb.x; }
            wmi[d] = make_float2(Ya.x, br);
        } else {
            int kp = LN - m;                 // = s0 + j4 + 4 - d  (own regs + nxt)
            float hl[4];
#pragma unroll
            for (int a = 0; a < 4; a++)
                hl[a] = (d==0) ? nxt[a] : (d==1) ? lowv[a].w : (d==2) ? lowv[a].z : lowv[a].y;
            float2 Xk = X[kp];
            float2 Wk, WkL;
            herm2(Xk, hl[0], hl[1], hl[2], hl[3],
                      mirS[0][jm], mirS[1][jm], mirS[2][jm], mirS[3][jm], hasB, Wk, WkL);
            wmi[d] = WkL;
        }
    }
    *(float4*)&Wp[mbase + e0]     = make_float4(wmi[0].x, wmi[0].y, wmi[1].x, wmi[1].y);
    *(float4*)&Wp[mbase + e0 + 2] = make_float4(wmi[2].x, wmi[2].y, wmi[3].x, wmi[3].y);
}

// ---- radix-4 quad butterfly (sign +1), in-place at p, p+H, p+2H, p+3H ----
// W1 = twid[2H+q], W2 = twid[H+q] = W1^2, W3 = W1*W2. Exactly == two radix-2 stages.
#define R4_BFLY(SRE, SIM, P, H, Q, TWID)                                        \
    {                                                                            \
        float2 W1 = TWID[2*(H) + (Q)];                                           \
        float2 W2 = TWID[(H) + (Q)];                                             \
        float2 W3 = cmulf(W1, W2);                                               \
        int p0 = SWZ(P), p1 = SWZ((P) + (H)), p2 = SWZ((P) + 2*(H)), p3 = SWZ((P) + 3*(H)); \
        float x0r = SRE[p0], x0i = SIM[p0];                                      \
        float x1r = SRE[p1], x1i = SIM[p1];                                      \
        float x2r = SRE[p2], x2i = SIM[p2];                                      \
        float x3r = SRE[p3], x3i = SIM[p3];                                      \
        float s02r = x0r + x2r, s02i = x0i + x2i;                                \
        float d02r = x0r - x2r, d02i = x0i - x2i;                                \
        float s13r = x1r + x3r, s13i = x1i + x3i;                                \
        float d13r = x1r - x3r, d13i = x1i - x3i;                                \
        SRE[p0] = s02r + s13r;  SIM[p0] = s02i + s13i;                           \
        float ar = s02r - s13r, ai = s02i - s13i;                                \
        SRE[p1] = ar*W2.x - ai*W2.y;  SIM[p1] = ar*W2.y + ai*W2.x;               \
        float br = d02r - d13i, bi = d02i + d13r;                                \
        SRE[p2] = br*W1.x - bi*W1.y;  SIM[p2] = br*W1.y + bi*W1.x;               \
        float cr = d02r + d13i, ci = d02i - d13r;                                \
        SRE[p3] = cr*W3.x - ci*W3.y;  SIM[p3] = cr*W3.y + ci*W3.x;               \
    }

// ---------------- column FFT: 16 cols/block, radix-4 DIF, sign +1, swizzled LDS ----
__global__ __launch_bounds__(1024) void kB(float2* __restrict__ D1) {
    __shared__ float sRe[16][545];
    __shared__ float sIm[16][545];
    __shared__ float2 twid[512];     // twid[h+q] = e^{+i pi q/h}
    int cg = blockIdx.x;             // column group 0..63
    int pl = blockIdx.y;             // pair within chunk
    float2* Dp = D1 + (size_t)pl * LN;
    unsigned c_base = 16u * cg;
    int t = threadIdx.x;

    if (t >= 1 && t < 512) {
        int h = 1 << (31 - __clz((unsigned)t));
        float ang = 3.14159265358979323846f * (float)(t - h) / (float)h;
        float s, c; __sincosf(ang, &s, &c);
        twid[t] = make_float2(c, s);
    }

    int cc = t & 15;
    int g  = (t >> 4) & 3;
    int w  = t >> 6;

    // ---- phase 1: load 16 columns; rows r = w + 16g + 64i ----
#pragma unroll
    for (int i = 0; i < 8; i++) {
        int r = w + (g << 4) + (i << 6);
        float2 v = Dp[(size_t)r * N2 + c_base + cc];
        int sp = SWZ(r);
        sRe[cc][sp] = v.x;
        sIm[cc][sp] = v.y;
    }
    __syncthreads();

    // ---- phase 2: 4 radix-4 stages + 1 radix-2; wave = column, lanes = quads ----
    int cc2 = t >> 6;                // 0..15 (wave-uniform)
    int l   = t & 63;
    float* re = sRe[cc2];
    float* im = sIm[cc2];
    for (int H = 128; H >= 2; H >>= 2) {   // radix-4 pairs (2H, H): (256,128)..(4,2)
#pragma unroll
        for (int i = 0; i < 2; i++) {
            int u = l + (i << 6);                // quad index 0..127
            int q = u & (H - 1);
            int p = ((u & ~(H - 1)) << 2) | q;
            R4_BFLY(re, im, p, H, q, twid);
        }
        __syncthreads();
    }
    // final radix-2 stage h=1: pairs (2j, 2j+1), twiddle (1,0) -> plain
#pragma unroll
    for (int i = 0; i < 4; i++) {
        int j = l + (i << 6);                // 0..255
        int p0 = SWZ(2*j), p1 = SWZ(2*j + 1);
        float ar = re[p0], ai = im[p0];
        float br = re[p1], bi = im[p1];
        re[p0] = ar + br;  im[p0] = ai + bi;
        re[p1] = ar - br;  im[p1] = ai - bi;
    }
    __syncthreads();

    // ---- phase 3: bitrev row, four-step twiddle, coalesced in-place write ----
    const float c2pi = 6.28318530717958647692f / (float)LN;
    unsigned truec = c_base + (unsigned)cc;
#pragma unroll
    for (int i = 0; i < 8; i++) {
        int pos = w + (g << 4) + (i << 6);           // 0..511
        unsigned jj = __brev((unsigned)pos) >> 23;   // bitrev9
        int sp = SWZ(pos);
        float rr = sRe[cc][sp], ii = sIm[cc][sp];
        unsigned prod = (jj * truec) & (unsigned)(LN - 1);
        float ang = c2pi * (float)prod;
        float s, c;
        __sincosf(ang, &s, &c);
        Dp[(size_t)jj * N2 + truec] = make_float2(rr*c - ii*s, rr*s + ii*c);
    }
}

// ---- kC: fused row-FFT (1024-pt hybrid radix-4/radix-2 DIF, sign +1) + finish ----
// radix-4 only at conflict-free strides (H=256,64); radix-2 for h=32..1 (proven 2-way).
__global__ __launch_bounds__(512) void kC(const float2* __restrict__ D1,
                                          float* __restrict__ comp,
                                          const float* __restrict__ alpha_comp,
                                          int pair0) {
    __shared__ float sRe[8][1057];
    __shared__ float sIm[8][1057];
    __shared__ float2 twid[1024];    // twid[h+q] = e^{+i pi q/h}
    int rg = blockIdx.x;             // row group 0..63
    int pl = blockIdx.y;
    int p  = pair0 + pl;
    int ca = 2*p, cb = 2*p + 1;
    const float2* Dp = D1 + (size_t)pl * LN;
    int jj0 = rg * 8;
    int t = threadIdx.x;
    for (int i = t; i < 1024; i += 512) {
        if (i >= 1) {
            int h = 1 << (31 - __clz((unsigned)i));
            float ang = 3.14159265358979323846f * (float)(i - h) / (float)h;
            float s, c; __sincosf(ang, &s, &c);
            twid[i] = make_float2(c, s);
        }
    }
    int w = t >> 6, l = t & 63;

    // ---- phase 1: wave w loads row jj0+w via float4 ----
    const float4* rowp = (const float4*)(Dp + (size_t)(jj0 + w) * N2);
#pragma unroll
    for (int i = 0; i < 8; i++) {
        int q4 = l + (i << 6);          // float4 index; complex elems 2q4, 2q4+1
        float4 v = rowp[q4];
        int a0 = SWZ(2*q4), a1 = SWZ(2*q4 + 1);
        sRe[w][a0] = v.x; sIm[w][a0] = v.y;
        sRe[w][a1] = v.z; sIm[w][a1] = v.w;
    }
    __syncthreads();

    // ---- phase 2: radix-4 stages H=256,64 (conflict-free) ----
    float* re = sRe[w];
    float* im = sIm[w];
    for (int H = 256; H >= 64; H >>= 2) {   // pairs (512,256),(128,64)
#pragma unroll
        for (int i = 0; i < 4; i++) {
            int u = l + (i << 6);                // quad index 0..255
            int q = u & (H - 1);
            int p4 = ((u & ~(H - 1)) << 2) | q;
            R4_BFLY(re, im, p4, H, q, twid);
        }
        __syncthreads();
    }
    // ---- radix-2 tail h=32..1 (round-18 proven mapping, ~2-way) ----
    for (int h = 32; h >= 1; h >>= 1) {
#pragma unroll
        for (int i = 0; i < 8; i++) {
            int j = l + (i << 6);                // 0..511
            int q = j & (h - 1);
            int base = ((j & ~(h - 1)) << 1) | q;
            float2 tw = twid[h + q];
            int p0 = SWZ(base), p1 = SWZ(base + h);
            float ar = re[p0], ai = im[p0];
            float br = re[p1], bi = im[p1];
            re[p0] = ar + br;  im[p0] = ai + bi;
            float dr = ar - br, di = ai - bi;
            re[p1] = dr*tw.x - di*tw.y;
            im[p1] = dr*tw.y + di*tw.x;
        }
        __syncthreads();
    }

    // ---- phase 3: m-ordered bitrev read, 1/L + powsign, transposed write ----
    float aa = alpha_comp[ca];
    float ab = (cb < NCH) ? alpha_comp[cb] : 1.f;
    const float invL = 1.f / (float)LN;
    int r  = t & 7;          // row within group
    int dm = (t >> 3) & 7;   // m sub-index
#pragma unroll
    for (int i = 0; i < 16; i++) {
        int m = (w << 7) + (i << 3) + dm;            // wave w covers m in [128w,128w+128)
        unsigned pp = __brev((unsigned)m) >> 22;     // bitrev10
        int sp = SWZ((int)pp);
        float rr = sRe[r][sp] * invL;
        float ii = sIm[r][sp] * invL;
        size_t n = (size_t)m * N1 + jj0 + r;         // time index
        comp[(size_t)ca * LN + n] = powsign(rr, aa);
        if (cb < NCH)
            comp[(size_t)cb * LN + n] = powsign(ii, ab);
    }
}

// ---------------- leaky IIR part 1: thread-per-20-samples + affine shuffle scan ----------
__global__ __launch_bounds__(256) void iir_part1(
    const float* __restrict__ comp, const float* __restrict__ alpha_leak,
    const float* __restrict__ li_kernel, float* __restrict__ out,
    float* __restrict__ carryOut) {
    __shared__ float win[SPB + SPB/TPW];   // pad every 20 (stride 21)
    __shared__ float wv[4], wg[4];
    int blk = blockIdx.x;
    int c = blockIdx.y;
    int t = threadIdx.x;
    float alpha = alpha_leak[0];
    float k0 = li_kernel[0], k1 = li_kernel[1];
    int base = blk * SPB;
    const int cap = NOUT * DSR;   // 524240
    const float* c0 = comp + (size_t)c * LN;
    const float* c1 = (c + 1 < NCH) ? comp + (size_t)(c + 1) * LN : nullptr;
    const float4 z4 = make_float4(0.f, 0.f, 0.f, 0.f);
    for (int i4 = 4*t; i4 < SPB; i4 += 1024) {
        int g = base + i4;
        float4 u0 = *(const float4*)&c0[g];
        float4 u1 = c1 ? *(const float4*)&c1[g] : z4;
        float vv[4] = {k0*u0.x + k1*u1.x, k0*u0.y + k1*u1.y,
                       k0*u0.z + k1*u1.z, k0*u0.w + k1*u1.w};
#pragma unroll
        for (int d = 0; d < 4; d++) {
            float v = fmaxf(vv[d], 0.f);
            if (g + d >= cap) v = 0.f;
            int i = i4 + d;
            win[i + i / TPW] = v;
        }
    }
    __syncthreads();
    float v = 0.f;
    int lbase = 21 * t;
#pragma unroll
    for (int i = 0; i < TPW; i++)
        v = fmaf(alpha, v, win[lbase + i]);
    float g = powf(alpha, (float)TPW);
    int lid = t & 63, wid = t >> 6;
#pragma unroll
    for (int d = 1; d < 64; d <<= 1) {
        float pv = __shfl_up(v, d);
        float pg = __shfl_up(g, d);
        if (lid >= d) { v = fmaf(g, pv, v); g = g * pg; }
    }
    if (lid == 63) { wv[wid] = v; wg[wid] = g; }
    __syncthreads();
    float cv = 0.f;
#pragma unroll
    for (int w = 0; w < 3; w++)
        if (w < wid) cv = wv[w] + wg[w] * cv;
    float vf = fmaf(g, cv, v);
    int nact = NOUT - blk * OB2; if (nact > OB2) nact = OB2;
    if ((t & 3) == 3) {
        int o = t >> 2;
        if (o < nact)
            out[(size_t)c * NOUT + blk * OB2 + o] = vf;
    }
    if (t == 4 * nact - 1)
        carryOut[c * NBLK + blk] = vf;
}

// ---------------- IIR part 2: per-channel carries (incl. circular wrap) ----------------
__global__ void iir_part2(const float* __restrict__ comp, const float* __restrict__ alpha_leak,
                          const float* __restrict__ li_kernel,
                          const float* __restrict__ carryOut, float* __restrict__ D) {
    int c = threadIdx.x;
    if (c >= NCH) return;
    float alpha = alpha_leak[0];
    float k0 = li_kernel[0], k1 = li_kernel[1];
    const float* c0 = comp + (size_t)c * LN;
    const float* c1 = (c + 1 < NCH) ? comp + (size_t)(c + 1) * LN : nullptr;
    float tail = 0.f, ap = 1.f;
    for (int j = 0; j < KTAIL; j++) {
        int g = LN - 1 - j;
        float u0 = c0[g];
        float u1 = c1 ? c1[g] : 0.f;
        float v = k0 * u0 + k1 * u1; v = v > 0.f ? v : 0.f;
        tail += ap * v;
        ap *= alpha;
    }
    float D0 = tail + ap * carryOut[c * NBLK + (NBLK - 1)]
             + powf(alpha, (float)(KTAIL + 2000)) * carryOut[c * NBLK + (NBLK - 2)];
    D[c * NBLK + 0] = D0;
    for (int b = 1; b < NBLK; b++)
        D[c * NBLK + b] = carryOut[c * NBLK + b - 1];
}

// ---------------- IIR part 3: add decayed carry into each output ----------------
__global__ void iir_part3(const float* __restrict__ D, const float* __restrict__ alpha_leak,
                          float* __restrict__ out) {
    int idx = blockIdx.x * 256 + threadIdx.x;
    if (idx >= NCH * NOUT) return;
    int c = idx / NOUT, m = idx - c * NOUT;
    int b = m / OB2, o = m - b * OB2;
    float alpha = alpha_leak[0];
    float beta = powf(alpha, (float)DSR);
    float dec = powf(beta, (float)(o + 1));
    out[idx] += dec * D[c * NBLK + b];
}

extern "C" void kernel_launch(void* const* d_in, const int* in_sizes, int n_in,
                              void* d_out, int out_size, void* d_ws, size_t ws_size,
                              hipStream_t stream) {
    const float* x  = (const float*)d_in[0];
    const float* Hr = (const float*)d_in[1];
    const float* Hi = (const float*)d_in[2];
    const float* ac = (const float*)d_in[3];
    const float* al = (const float*)d_in[4];
    const float* li = (const float*)d_in[5];
    float* out = (float*)d_out;

    char* ws = (char*)d_ws;
    size_t off = 0;
    auto alloc = [&](size_t bytes) -> void* {
        void* p = ws + off;
        off += (bytes + 255) & ~(size_t)255;
        return p;
    };
    float2* Xf     = (float2*)alloc((size_t)LN * sizeof(float2));
    float*  comp   = (float*) alloc((size_t)NCH * LN * sizeof(float));
    float*  cOut   = (float*) alloc((size_t)NCH * NBLK * sizeof(float));
    float*  Dbuf   = (float*) alloc((size_t)NCH * NBLK * sizeof(float));
    size_t remain = (ws_size > off) ? (ws_size - off) : 0;
    int chunk = (int)(remain / ((size_t)LN * sizeof(float2)));
    if (chunk > NPAIR) chunk = NPAIR;
    if (chunk < 2)     chunk = 2;
    float2* bufA = (float2*)alloc((size_t)chunk * LN * sizeof(float2));

    dim3 tb(32, 8, 1);

    // ---- forward FFT of x (four-step with transposes; small, one signal) ----
    float2* fA = bufA;
    float2* fB = bufA + LN;
    pack_x<<<LN / 256, 256, 0, stream>>>(x, fA);
    transpose_c<<<dim3(N2/32, N1/32, 1), tb, 0, stream>>>(fA, fB, N1, N2);
    fft_rows<N1, -1, 1><<<N2, 256, 0, stream>>>(fB, fB, N2);
    transpose_c<<<dim3(N1/32, N2/32, 1), tb, 0, stream>>>(fB, fA, N2, N1);
    fft_rows<N2, -1, 0><<<N1, 256, 0, stream>>>(fA, fA, N1);
    transpose_c<<<dim3(N2/32, N1/32, 1), tb, 0, stream>>>(fA, Xf, N1, N2);

    // ---- batched inverse FFTs: build_w6 -> radix-4 colFFT -> hybrid rowFFT+finish ----
    for (int ci = 0; ci < NPAIR; ci += chunk) {
        int np = NPAIR - ci; if (np > chunk) np = chunk;
        build_w6<<<dim3(LN/2/SB, np), 256, 0, stream>>>(Hr, Hi, Xf, bufA, ci);
        kB<<<dim3(64, np), 1024, 0, stream>>>(bufA);
        kC<<<dim3(64, np), 512, 0, stream>>>(bufA, comp, ac, ci);
    }

    // ---- leaky integration (time-domain, exact to fp precision) + downsample ----
    iir_part1<<<dim3(NBLK, NCH, 1), 256, 0, stream>>>(comp, al, li, out, cOut);
    iir_part2<<<1, 256, 0, stream>>>(comp, al, li, cOut, Dbuf);
    iir_part3<<<(NCH * NOUT + 255) / 256, 256, 0, stream>>>(Dbuf, al, out);
}

// Round 21
// 633.168 us; speedup vs baseline: 1.0158x; 1.0158x over previous
//
#include <hip/hip_runtime.h>
#include <math.h>

#define LN    524288        // signal length, 2^19
#define N1    512           // first-FFT length (column FFT)
#define N2    1024          // second-FFT length (row FFT)
#define NCH   129
#define DSR   80            // downsample rate
#define NOUT  6553          // output frames per channel
#define OB2   64            // outputs per IIR block
#define NBLK  103           // ceil(NOUT/OB2)
#define SPB   (OB2*DSR)     // 5120 samples per IIR block
#define TPW   20            // samples per thread in IIR
#define NPAIR 65            // ceil(129/2) channel pairs
#define KTAIL 48            // LN - NOUT*DSR
#define SB    1024          // build_w6 segment length per block
#define LMAP(i) ((i) + ((i) >> 3))   // LDS bank-spread map (2-way max)
#define SWZ(p)  ((p) ^ ((((p) >> 5) & 1) * 31))   // bank swizzle

__device__ __forceinline__ float2 cmulf(float2 a, float2 b) {
    return make_float2(a.x*b.x - a.y*b.y, a.x*b.y + a.y*b.x);
}

// fast |x|^a * sign(x): hardware log2/exp2 (x=0 -> -inf -> 0, correct)
__device__ __forceinline__ float powsign(float x, float a) {
    float m = __builtin_amdgcn_exp2f(a * __builtin_amdgcn_logf(fabsf(x)));
    return copysignf(m, x);
}

// ---------------- pack real x into complex buffer ----------------
__global__ void pack_x(const float* __restrict__ x, float2* __restrict__ dst) {
    int i = blockIdx.x * 256 + threadIdx.x;
    dst[i] = make_float2(x[i], 0.f);
}

// ---------------- tiled complex transpose (forward path only) ----------------
__global__ void transpose_c(const float2* __restrict__ src, float2* __restrict__ dst,
                            int R, int Cc) {
    __shared__ float2 tile[32][33];
    size_t boff = (size_t)blockIdx.z * LN;
    src += boff; dst += boff;
    int x  = blockIdx.x * 32 + threadIdx.x;
    int y0 = blockIdx.y * 32 + threadIdx.y;
#pragma unroll
    for (int i = 0; i < 32; i += 8)
        tile[threadIdx.y + i][threadIdx.x] = src[(size_t)(y0 + i) * Cc + x];
    __syncthreads();
    int xo  = blockIdx.y * 32 + threadIdx.x;
    int yo0 = blockIdx.x * 32 + threadIdx.y;
#pragma unroll
    for (int i = 0; i < 32; i += 8)
        dst[(size_t)(yo0 + i) * R + xo] = tile[threadIdx.x][threadIdx.y + i];
}

// ---------------- LDS Stockham radix-2 row FFT (forward path only) -----
template<int M, int SIGN, int TW>
__global__ __launch_bounds__(256) void fft_rows(const float2* __restrict__ src,
                                                float2* __restrict__ dst,
                                                int rows_per_batch) {
    __shared__ __align__(16) float2 ping[M];
    __shared__ __align__(16) float2 pong[M];
    __shared__ float2 twid[M];
    size_t rowg = blockIdx.x;
    const float2* srow = src + rowg * M;
    float2* drow = dst + rowg * M;
    int row = (int)(rowg % (size_t)rows_per_batch);
    int t = threadIdx.x;
    const float4* s4 = (const float4*)srow;
    for (int ii = t; ii < M/2; ii += 256)
        *(float4*)&ping[2*ii] = s4[ii];
    for (int i = t; i < M; i += 256) {
        if (i >= 1) {
            int h = 1 << (31 - __clz((unsigned)i));
            float ang = (float)SIGN * 3.14159265358979323846f * (float)(i - h) / (float)h;
            float s, c; __sincosf(ang, &s, &c);
            twid[i] = make_float2(c, s);
        }
    }
    __syncthreads();
    float2* a = ping;
    float2* b = pong;
    for (int Ns = 1; Ns < M; Ns <<= 1) {
        for (int j = t; j < M/2; j += 256) {
            int jm = j & (Ns - 1);
            float2 v0 = a[j];
            float2 v1 = a[j + M/2];
            float2 tw = twid[Ns + jm];
            float2 w = make_float2(v1.x*tw.x - v1.y*tw.y, v1.x*tw.y + v1.y*tw.x);
            int d0 = ((j & ~(Ns - 1)) << 1) | jm;
            b[d0]      = make_float2(v0.x + w.x, v0.y + w.y);
            b[d0 + Ns] = make_float2(v0.x - w.x, v0.y - w.y);
        }
        __syncthreads();
        float2* tmp = a; a = b; b = tmp;
    }
    if (TW) {
        const float c2pi = 6.28318530717958647692f / (float)LN;
        for (int i = t; i < M; i += 256) {
            float2 v = a[i];
            unsigned prod = ((unsigned)row * (unsigned)i) & (unsigned)(LN - 1);
            float ang = (float)SIGN * c2pi * (float)prod;
            float s, c;
            __sincosf(ang, &s, &c);
            drow[i] = make_float2(v.x*c - v.y*s, v.x*s + v.y*c);
        }
    } else {
        float4* d4 = (float4*)drow;
        for (int ii = t; ii < M/2; ii += 256)
            d4[ii] = *(const float4*)&a[2*ii];
    }
}

// ---------------- Hermitian-combine W[k],W[L-k] from H,X ----------------
__device__ __forceinline__ void herm2(float2 X1,
                                      float har,  float hai,  float hbr,  float hbi,
                                      float har2, float hai2, float hbr2, float hbi2,
                                      bool hasB, float2& Wk, float2& WkL) {
    float2 a1 = make_float2(har*X1.x - hai*X1.y, har*X1.y + hai*X1.x);
    float2 a2 = make_float2(har2*X1.x + hai2*X1.y, hai2*X1.x - har2*X1.y);
    float yar = 0.5f*(a1.x + a2.x), yai = 0.5f*(a1.y - a2.y);
    float ybr = 0.f, ybi = 0.f;
    if (hasB) {
        float2 b1 = make_float2(hbr*X1.x - hbi*X1.y, hbr*X1.y + hbi*X1.x);
        float2 b2 = make_float2(hbr2*X1.x + hbi2*X1.y, hbi2*X1.x - hbr2*X1.y);
        ybr = 0.5f*(b1.x + b2.x); ybi = 0.5f*(b1.y - b2.y);
    }
    Wk  = make_float2(yar - ybi, yai + ybr);
    WkL = make_float2(yar + ybi, ybr - yai);
}

// ---- build_w6: Hermitian pairing, mirror seg in LDS, low seg in REGISTERS only ----
__global__ __launch_bounds__(256) void build_w6(const float* __restrict__ Hr,
                                                const float* __restrict__ Hi,
                                                const float2* __restrict__ X,
                                                float2* __restrict__ W, int pair0) {
    __shared__ float mirS[4][1160];
    int s0 = blockIdx.x * SB;            // [0, LN/2)
    int pl = blockIdx.y;
    int p  = pair0 + pl;
    int ca = 2*p, cb = 2*p + 1;
    bool hasB = (cb < NCH);
    const float* Hs0 = Hr + (size_t)ca * LN;
    const float* Hs1 = Hi + (size_t)ca * LN;
    const float* Hs2 = hasB ? (Hr + (size_t)cb * LN) : Hs0;
    const float* Hs3 = hasB ? (Hi + (size_t)cb * LN) : Hs1;
    const float* Hs[4] = {Hs0, Hs1, Hs2, Hs3};
    float2* Wp = W + (size_t)pl * LN;
    int t = threadIdx.x;
    int j4 = 4 * t;
    int mbase = LN - s0 - SB;            // mirror segment start

    float4 lowv[4];
#pragma unroll
    for (int a = 0; a < 4; a++) {
        lowv[a] = *(const float4*)&Hs[a][s0 + j4];
        float4 mv = *(const float4*)&Hs[a][mbase + j4];
        int lm = LMAP(j4);
        mirS[a][lm+0] = mv.x; mirS[a][lm+1] = mv.y; mirS[a][lm+2] = mv.z; mirS[a][lm+3] = mv.w;
    }
    if (t == 1 && s0 > 0) {
#pragma unroll
        for (int a = 0; a < 4; a++) mirS[a][LMAP(SB)] = Hs[a][LN - s0];
    }
    float nxt[4];
#pragma unroll
    for (int a = 0; a < 4; a++) nxt[a] = __shfl_down(lowv[a].x, 1);
    if ((t & 63) == 63) {
#pragma unroll
        for (int a = 0; a < 4; a++) nxt[a] = Hs[a][s0 + j4 + 4];
    }
    __syncthreads();

    float4 xa = *(const float4*)&X[s0 + j4];
    float4 xb = *(const float4*)&X[s0 + j4 + 2];
    float2 wlo[4];
#pragma unroll
    for (int d = 0; d < 4; d++) {
        int k = s0 + j4 + d;
        float2 Xk = (d == 0) ? make_float2(xa.x, xa.y) :
                    (d == 1) ? make_float2(xa.z, xa.w) :
                    (d == 2) ? make_float2(xb.x, xb.y) : make_float2(xb.z, xb.w);
        float hl[4] = { (d==0)?lowv[0].x:(d==1)?lowv[0].y:(d==2)?lowv[0].z:lowv[0].w,
                        (d==0)?lowv[1].x:(d==1)?lowv[1].y:(d==2)?lowv[1].z:lowv[1].w,
                        (d==0)?lowv[2].x:(d==1)?lowv[2].y:(d==2)?lowv[2].z:lowv[2].w,
                        (d==0)?lowv[3].x:(d==1)?lowv[3].y:(d==2)?lowv[3].z:lowv[3].w };
        if (k == 0) {
            float2 Ya = cmulf(make_float2(hl[0], hl[1]), Xk);
            float br = 0.f;
            if (hasB) { float2 Yb = cmulf(make_float2(hl[2], hl[3]), Xk); br = Yb.x; }
            wlo[d] = make_float2(Ya.x, br);
        } else {
            int jm = LMAP(SB - j4 - d);
            float2 Wk, WkL;
            herm2(Xk, hl[0], hl[1], hl[2], hl[3],
                      mirS[0][jm], mirS[1][jm], mirS[2][jm], mirS[3][jm], hasB, Wk, WkL);
            wlo[d] = Wk;
        }
    }
    *(float4*)&Wp[s0 + j4]     = make_float4(wlo[0].x, wlo[0].y, wlo[1].x, wlo[1].y);
    *(float4*)&Wp[s0 + j4 + 2] = make_float4(wlo[2].x, wlo[2].y, wlo[3].x, wlo[3].y);

    int e0 = SB - 4 - j4;
    float2 wmi[4];
#pragma unroll
    for (int d = 0; d < 4; d++) {
        int ee = e0 + d;
        int m  = mbase + ee;
        int jm = LMAP(ee);
        if (m == LN/2) {
            float2 Xv = X[LN/2];
            float2 Ya = cmulf(make_float2(mirS[0][jm], mirS[1][jm]), Xv);
            float br = 0.f;
            if (hasB) { float2 Yb = cmulf(make_float2(mirS[2][jm], mirS[3][jm]), Xv); br = Yb.x; }
            wmi[d] = make_float2(Ya.x, br);
        } else {
            int kp = LN - m;                 // = s0 + j4 + 4 - d  (own regs + nxt)
            float hl[4];
#pragma unroll
            for (int a = 0; a < 4; a++)
                hl[a] = (d==0) ? nxt[a] : (d==1) ? lowv[a].w : (d==2) ? lowv[a].z : lowv[a].y;
            float2 Xk = X[kp];
            float2 Wk, WkL;
            herm2(Xk, hl[0], hl[1], hl[2], hl[3],
                      mirS[0][jm], mirS[1][jm], mirS[2][jm], mirS[3][jm], hasB, Wk, WkL);
            wmi[d] = WkL;
        }
    }
    *(float4*)&Wp[mbase + e0]     = make_float4(wmi[0].x, wmi[0].y, wmi[1].x, wmi[1].y);
    *(float4*)&Wp[mbase + e0 + 2] = make_float4(wmi[2].x, wmi[2].y, wmi[3].x, wmi[3].y);
}

// ---- radix-4 quad butterfly (sign +1), in-place at p, p+H, p+2H, p+3H ----
#define R4_BFLY(SRE, SIM, P, H, Q, TWID)                                        \
    {                                                                            \
        float2 W1 = TWID[2*(H) + (Q)];                                           \
        float2 W2 = TWID[(H) + (Q)];                                             \
        float2 W3 = cmulf(W1, W2);                                               \
        int p0 = SWZ(P), p1 = SWZ((P) + (H)), p2 = SWZ((P) + 2*(H)), p3 = SWZ((P) + 3*(H)); \
        float x0r = SRE[p0], x0i = SIM[p0];                                      \
        float x1r = SRE[p1], x1i = SIM[p1];                                      \
        float x2r = SRE[p2], x2i = SIM[p2];                                      \
        float x3r = SRE[p3], x3i = SIM[p3];                                      \
        float s02r = x0r + x2r, s02i = x0i + x2i;                                \
        float d02r = x0r - x2r, d02i = x0i - x2i;                                \
        float s13r = x1r + x3r, s13i = x1i + x3i;                                \
        float d13r = x1r - x3r, d13i = x1i - x3i;                                \
        SRE[p0] = s02r + s13r;  SIM[p0] = s02i + s13i;                           \
        float ar = s02r - s13r, ai = s02i - s13i;                                \
        SRE[p1] = ar*W2.x - ai*W2.y;  SIM[p1] = ar*W2.y + ai*W2.x;               \
        float br = d02r - d13i, bi = d02i + d13r;                                \
        SRE[p2] = br*W1.x - bi*W1.y;  SIM[p2] = br*W1.y + bi*W1.x;               \
        float cr = d02r + d13i, ci = d02i - d13r;                                \
        SRE[p3] = cr*W3.x - ci*W3.y;  SIM[p3] = cr*W3.y + ci*W3.x;               \
    }

// ---------------- column FFT: 16 cols/block, radix-4 DIF (measured best) ----
__global__ __launch_bounds__(1024) void kB(float2* __restrict__ D1) {
    __shared__ float sRe[16][545];
    __shared__ float sIm[16][545];
    __shared__ float2 twid[512];     // twid[h+q] = e^{+i pi q/h}
    int cg = blockIdx.x;             // column group 0..63
    int pl = blockIdx.y;             // pair within chunk
    float2* Dp = D1 + (size_t)pl * LN;
    unsigned c_base = 16u * cg;
    int t = threadIdx.x;

    if (t >= 1 && t < 512) {
        int h = 1 << (31 - __clz((unsigned)t));
        float ang = 3.14159265358979323846f * (float)(t - h) / (float)h;
        float s, c; __sincosf(ang, &s, &c);
        twid[t] = make_float2(c, s);
    }

    int cc = t & 15;
    int g  = (t >> 4) & 3;
    int w  = t >> 6;

    // ---- phase 1: load 16 columns; rows r = w + 16g + 64i ----
#pragma unroll
    for (int i = 0; i < 8; i++) {
        int r = w + (g << 4) + (i << 6);
        float2 v = Dp[(size_t)r * N2 + c_base + cc];
        int sp = SWZ(r);
        sRe[cc][sp] = v.x;
        sIm[cc][sp] = v.y;
    }
    __syncthreads();

    // ---- phase 2: 4 radix-4 stages + 1 radix-2; wave = column, lanes = quads ----
    int cc2 = t >> 6;                // 0..15 (wave-uniform)
    int l   = t & 63;
    float* re = sRe[cc2];
    float* im = sIm[cc2];
    for (int H = 128; H >= 2; H >>= 2) {   // radix-4 pairs (2H, H): (256,128)..(4,2)
#pragma unroll
        for (int i = 0; i < 2; i++) {
            int u = l + (i << 6);                // quad index 0..127
            int q = u & (H - 1);
            int p = ((u & ~(H - 1)) << 2) | q;
            R4_BFLY(re, im, p, H, q, twid);
        }
        __syncthreads();
    }
    // final radix-2 stage h=1: pairs (2j, 2j+1), twiddle (1,0) -> plain
#pragma unroll
    for (int i = 0; i < 4; i++) {
        int j = l + (i << 6);                // 0..255
        int p0 = SWZ(2*j), p1 = SWZ(2*j + 1);
        float ar = re[p0], ai = im[p0];
        float br = re[p1], bi = im[p1];
        re[p0] = ar + br;  im[p0] = ai + bi;
        re[p1] = ar - br;  im[p1] = ai - bi;
    }
    __syncthreads();

    // ---- phase 3: bitrev row, four-step twiddle, coalesced in-place write ----
    const float c2pi = 6.28318530717958647692f / (float)LN;
    unsigned truec = c_base + (unsigned)cc;
#pragma unroll
    for (int i = 0; i < 8; i++) {
        int pos = w + (g << 4) + (i << 6);           // 0..511
        unsigned jj = __brev((unsigned)pos) >> 23;   // bitrev9
        int sp = SWZ(pos);
        float rr = sRe[cc][sp], ii = sIm[cc][sp];
        unsigned prod = (jj * truec) & (unsigned)(LN - 1);
        float ang = c2pi * (float)prod;
        float s, c;
        __sincosf(ang, &s, &c);
        Dp[(size_t)jj * N2 + truec] = make_float2(rr*c - ii*s, rr*s + ii*c);
    }
}

// ---- kC: fused row-FFT (1024-pt radix-2 DIF, sign +1 — measured best) + finish ----
__global__ __launch_bounds__(512) void kC(const float2* __restrict__ D1,
                                          float* __restrict__ comp,
                                          const float* __restrict__ alpha_comp,
                                          int pair0) {
    __shared__ float sRe[8][1057];
    __shared__ float sIm[8][1057];
    __shared__ float2 twid[1024];    // twid[h+q] = e^{+i pi q/h}
    int rg = blockIdx.x;             // row group 0..63
    int pl = blockIdx.y;
    int p  = pair0 + pl;
    int ca = 2*p, cb = 2*p + 1;
    const float2* Dp = D1 + (size_t)pl * LN;
    int jj0 = rg * 8;
    int t = threadIdx.x;
    for (int i = t; i < 1024; i += 512) {
        if (i >= 1) {
            int h = 1 << (31 - __clz((unsigned)i));
            float ang = 3.14159265358979323846f * (float)(i - h) / (float)h;
            float s, c; __sincosf(ang, &s, &c);
            twid[i] = make_float2(c, s);
        }
    }
    int w = t >> 6, l = t & 63;

    // ---- phase 1: wave w loads row jj0+w via float4 ----
    const float4* rowp = (const float4*)(Dp + (size_t)(jj0 + w) * N2);
#pragma unroll
    for (int i = 0; i < 8; i++) {
        int q4 = l + (i << 6);          // float4 index; complex elems 2q4, 2q4+1
        float4 v = rowp[q4];
        int a0 = SWZ(2*q4), a1 = SWZ(2*q4 + 1);
        sRe[w][a0] = v.x; sIm[w][a0] = v.y;
        sRe[w][a1] = v.z; sIm[w][a1] = v.w;
    }
    __syncthreads();

    // ---- phase 2: 10-stage in-place radix-2 DIF (sign +1); wave = row, lanes = j ----
    float* re = sRe[w];
    float* im = sIm[w];
    for (int h = 512; h >= 1; h >>= 1) {
#pragma unroll
        for (int i = 0; i < 8; i++) {
            int j = l + (i << 6);                // 0..511
            int q = j & (h - 1);
            int base = ((j & ~(h - 1)) << 1) | q;
            float2 tw = twid[h + q];
            int p0 = SWZ(base), p1 = SWZ(base + h);
            float ar = re[p0], ai = im[p0];
            float br = re[p1], bi = im[p1];
            re[p0] = ar + br;  im[p0] = ai + bi;
            float dr = ar - br, di = ai - bi;
            re[p1] = dr*tw.x - di*tw.y;
            im[p1] = dr*tw.y + di*tw.x;
        }
        __syncthreads();
    }

    // ---- phase 3: m-ordered bitrev read, 1/L + powsign, transposed write ----
    float aa = alpha_comp[ca];
    float ab = (cb < NCH) ? alpha_comp[cb] : 1.f;
    const float invL = 1.f / (float)LN;
    int r  = t & 7;          // row within group
    int dm = (t >> 3) & 7;   // m sub-index
#pragma unroll
    for (int i = 0; i < 16; i++) {
        int m = (w << 7) + (i << 3) + dm;            // wave w covers m in [128w,128w+128)
        unsigned pp = __brev((unsigned)m) >> 22;     // bitrev10
        int sp = SWZ((int)pp);
        float rr = sRe[r][sp] * invL;
        float ii = sIm[r][sp] * invL;
        size_t n = (size_t)m * N1 + jj0 + r;         // time index
        comp[(size_t)ca * LN + n] = powsign(rr, aa);
        if (cb < NCH)
            comp[(size_t)cb * LN + n] = powsign(ii, ab);
    }
}

// ---------------- leaky IIR part 1: thread-per-20-samples + affine shuffle scan ----------
__global__ __launch_bounds__(256) void iir_part1(
    const float* __restrict__ comp, const float* __restrict__ alpha_leak,
    const float* __restrict__ li_kernel, float* __restrict__ out,
    float* __restrict__ carryOut) {
    __shared__ float win[SPB + SPB/TPW];   // pad every 20 (stride 21)
    __shared__ float wv[4], wg[4];
    int blk = blockIdx.x;
    int c = blockIdx.y;
    int t = threadIdx.x;
    float alpha = alpha_leak[0];
    float k0 = li_kernel[0], k1 = li_kernel[1];
    int base = blk * SPB;
    const int cap = NOUT * DSR;   // 524240
    const float* c0 = comp + (size_t)c * LN;
    const float* c1 = (c + 1 < NCH) ? comp + (size_t)(c + 1) * LN : nullptr;
    const float4 z4 = make_float4(0.f, 0.f, 0.f, 0.f);
    for (int i4 = 4*t; i4 < SPB; i4 += 1024) {
        int g = base + i4;
        float4 u0 = *(const float4*)&c0[g];
        float4 u1 = c1 ? *(const float4*)&c1[g] : z4;
        float vv[4] = {k0*u0.x + k1*u1.x, k0*u0.y + k1*u1.y,
                       k0*u0.z + k1*u1.z, k0*u0.w + k1*u1.w};
#pragma unroll
        for (int d = 0; d < 4; d++) {
            float v = fmaxf(vv[d], 0.f);
            if (g + d >= cap) v = 0.f;
            int i = i4 + d;
            win[i + i / TPW] = v;
        }
    }
    __syncthreads();
    float v = 0.f;
    int lbase = 21 * t;
#pragma unroll
    for (int i = 0; i < TPW; i++)
        v = fmaf(alpha, v, win[lbase + i]);
    float g = powf(alpha, (float)TPW);
    int lid = t & 63, wid = t >> 6;
#pragma unroll
    for (int d = 1; d < 64; d <<= 1) {
        float pv = __shfl_up(v, d);
        float pg = __shfl_up(g, d);
        if (lid >= d) { v = fmaf(g, pv, v); g = g * pg; }
    }
    if (lid == 63) { wv[wid] = v; wg[wid] = g; }
    __syncthreads();
    float cv = 0.f;
#pragma unroll
    for (int w = 0; w < 3; w++)
        if (w < wid) cv = wv[w] + wg[w] * cv;
    float vf = fmaf(g, cv, v);
    int nact = NOUT - blk * OB2; if (nact > OB2) nact = OB2;
    if ((t & 3) == 3) {
        int o = t >> 2;
        if (o < nact)
            out[(size_t)c * NOUT + blk * OB2 + o] = vf;
    }
    if (t == 4 * nact - 1)
        carryOut[c * NBLK + blk] = vf;
}

// ---------------- IIR part 2: per-channel carries (incl. circular wrap) ----------------
__global__ void iir_part2(const float* __restrict__ comp, const float* __restrict__ alpha_leak,
                          const float* __restrict__ li_kernel,
                          const float* __restrict__ carryOut, float* __restrict__ D) {
    int c = threadIdx.x;
    if (c >= NCH) return;
    float alpha = alpha_leak[0];
    float k0 = li_kernel[0], k1 = li_kernel[1];
    const float* c0 = comp + (size_t)c * LN;
    const float* c1 = (c + 1 < NCH) ? comp + (size_t)(c + 1) * LN : nullptr;
    float tail = 0.f, ap = 1.f;
    for (int j = 0; j < KTAIL; j++) {
        int g = LN - 1 - j;
        float u0 = c0[g];
        float u1 = c1 ? c1[g] : 0.f;
        float v = k0 * u0 + k1 * u1; v = v > 0.f ? v : 0.f;
        tail += ap * v;
        ap *= alpha;
    }
    float D0 = tail + ap * carryOut[c * NBLK + (NBLK - 1)]
             + powf(alpha, (float)(KTAIL + 2000)) * carryOut[c * NBLK + (NBLK - 2)];
    D[c * NBLK + 0] = D0;
    for (int b = 1; b < NBLK; b++)
        D[c * NBLK + b] = carryOut[c * NBLK + b - 1];
}

// ---------------- IIR part 3: add decayed carry into each output ----------------
__global__ void iir_part3(const float* __restrict__ D, const float* __restrict__ alpha_leak,
                          float* __restrict__ out) {
    int idx = blockIdx.x * 256 + threadIdx.x;
    if (idx >= NCH * NOUT) return;
    int c = idx / NOUT, m = idx - c * NOUT;
    int b = m / OB2, o = m - b * OB2;
    float alpha = alpha_leak[0];
    float beta = powf(alpha, (float)DSR);
    float dec = powf(beta, (float)(o + 1));
    out[idx] += dec * D[c * NBLK + b];
}

extern "C" void kernel_launch(void* const* d_in, const int* in_sizes, int n_in,
                              void* d_out, int out_size, void* d_ws, size_t ws_size,
                              hipStream_t stream) {
    const float* x  = (const float*)d_in[0];
    const float* Hr = (const float*)d_in[1];
    const float* Hi = (const float*)d_in[2];
    const float* ac = (const float*)d_in[3];
    const float* al = (const float*)d_in[4];
    const float* li = (const float*)d_in[5];
    float* out = (float*)d_out;

    char* ws = (char*)d_ws;
    size_t off = 0;
    auto alloc = [&](size_t bytes) -> void* {
        void* p = ws + off;
        off += (bytes + 255) & ~(size_t)255;
        return p;
    };
    float2* Xf     = (float2*)alloc((size_t)LN * sizeof(float2));
    float*  comp   = (float*) alloc((size_t)NCH * LN * sizeof(float));
    float*  cOut   = (float*) alloc((size_t)NCH * NBLK * sizeof(float));
    float*  Dbuf   = (float*) alloc((size_t)NCH * NBLK * sizeof(float));
    size_t remain = (ws_size > off) ? (ws_size - off) : 0;
    int chunk = (int)(remain / ((size_t)LN * sizeof(float2)));
    if (chunk > NPAIR) chunk = NPAIR;
    if (chunk < 2)     chunk = 2;
    float2* bufA = (float2*)alloc((size_t)chunk * LN * sizeof(float2));

    dim3 tb(32, 8, 1);

    // ---- forward FFT of x (four-step with transposes; small, one signal) ----
    float2* fA = bufA;
    float2* fB = bufA + LN;
    pack_x<<<LN / 256, 256, 0, stream>>>(x, fA);
    transpose_c<<<dim3(N2/32, N1/32, 1), tb, 0, stream>>>(fA, fB, N1, N2);
    fft_rows<N1, -1, 1><<<N2, 256, 0, stream>>>(fB, fB, N2);
    transpose_c<<<dim3(N1/32, N2/32, 1), tb, 0, stream>>>(fB, fA, N2, N1);
    fft_rows<N2, -1, 0><<<N1, 256, 0, stream>>>(fA, fA, N1);
    transpose_c<<<dim3(N2/32, N1/32, 1), tb, 0, stream>>>(fA, Xf, N1, N2);

    // ---- batched inverse FFTs: build_w6 -> radix-4 colFFT -> radix-2 rowFFT+finish ----
    for (int ci = 0; ci < NPAIR; ci += chunk) {
        int np = NPAIR - ci; if (np > chunk) np = chunk;
        build_w6<<<dim3(LN/2/SB, np), 256, 0, stream>>>(Hr, Hi, Xf, bufA, ci);
        kB<<<dim3(64, np), 1024, 0, stream>>>(bufA);
        kC<<<dim3(64, np), 512, 0, stream>>>(bufA, comp, ac, ci);
    }

    // ---- leaky integration (time-domain, exact to fp precision) + downsample ----
    iir_part1<<<dim3(NBLK, NCH, 1), 256, 0, stream>>>(comp, al, li, out, cOut);
    iir_part2<<<1, 256, 0, stream>>>(comp, al, li, cOut, Dbuf);
    iir_part3<<<(NCH * NOUT + 255) / 256, 256, 0, stream>>>(Dbuf, al, out);
}